// Round 10
// baseline (91.675 us; speedup 1.0000x reference)
//
#include <hip/hip_runtime.h>
#include <hip/hip_bf16.h>
#include <math.h>

// Problem constants
#define LSEQ   512
#define DDIM   1024
#define KDIM   256       // K
#define COLS   256       // LATENT
#define ROWS   4096      // B * NTOK * NSEC
#define COEF   0.1f

// R10 tiling: block 64 rows x 64 cols, 512 threads = 8 waves (2/SIMD), each
// wave a 16x32 strip (2 MFMA tiles). Full K=256, ONE barrier. Grid 64x4 = 256
// blocks = 1/CU. vs R9 (32x64, 512 blocks): total staging halves
// (256x64KB=16MB vs 24MB), converts 12M->8M, slots/thread 12->8, ramp halves;
// waves/SIMD unchanged at 2 (R6's failure mode was 1 wave/SIMD).
#define TR     64
#define TC     64

// Semantics collapse (verified R1-R9): spectral chain ==
//   out[row,o] = tanh( scale(row)*dot(enc_row, W[o,:]) + b[o] )
// 1-pass bf16 MFMA verified safe: absmax 0.0103 < 2e-2 (R8/R9).
// LDS: 16B slot = one 8-bf16 MFMA frag; stored[r][p] = logical[r][p ^ (r&15)]
// -> conflict-free b128 reads and writes, zero padding, 64 KB, one barrier.
// Known-bad: fp32 LDS-LDS (~19.6us); global/scalar W inner loop (45-47us);
// 1 wave/SIMD (R6); inline Dekker split (R7); 2-kernel bf16 (R8).

typedef __attribute__((ext_vector_type(8))) short short8;    // 8 bf16 frag
typedef __attribute__((ext_vector_type(4))) float float4v;   // MFMA C/D

__device__ __forceinline__ float tanh_fast(float x) {
    // 1 - 2/(e^{2x}+1): exact +/-inf limits, ~1e-6 abs err via v_exp_f32
    return 1.0f - 2.0f / (__expf(2.0f * x) + 1.0f);
}

__device__ __forceinline__ uint4 pack8_bf16(const float4 x0, const float4 x1) {
    union { __hip_bfloat162 h2[4]; uint4 u4; } pk;
    pk.h2[0] = __float22bfloat162_rn(make_float2(x0.x, x0.y));
    pk.h2[1] = __float22bfloat162_rn(make_float2(x0.z, x0.w));
    pk.h2[2] = __float22bfloat162_rn(make_float2(x1.x, x1.y));
    pk.h2[3] = __float22bfloat162_rn(make_float2(x1.z, x1.w));
    return pk.u4;
}

__global__ __launch_bounds__(512, 1)
void spectral_mfma_kernel(const float* __restrict__ enc,
                          const float* __restrict__ W,
                          const float* __restrict__ bias,
                          float* __restrict__ out) {
    // shorts; A rows at [0,16384) (64 x 256), W rows at [16384,32768) (64 x 256)
    __shared__ unsigned short SH[32768];   // 64 KB exactly (R5 proved this size)

    const int t    = threadIdx.x;
    const int lane = t & 63;
    const int wv   = t >> 6;               // 0..7
    const int tile_r = blockIdx.x * TR;    // 64 | 128: no batch-segment straddle
    const int tile_c = blockIdx.y * TC;

    const float* __restrict__ srcA = enc + (size_t)(tile_r >> 7) * (size_t)(LSEQ * DDIM)
                                         + (size_t)(tile_r & 127) * KDIM;
    const float* __restrict__ srcW = W + (size_t)tile_c * KDIM;

    // ---- stage A: 2048 slots (64 rows x 32), 4 per thread ----
    #pragma unroll
    for (int i = 0; i < 4; ++i) {
        const int q = t + i * 512;
        const int r = q >> 5, s = q & 31;
        const float* g = srcA + (size_t)r * KDIM + ((s ^ (r & 15)) * 8);
        const uint4 v = pack8_bf16(*(const float4*)g, *(const float4*)(g + 4));
        *(uint4*)&SH[(r * 32 + s) * 8] = v;   // stored[r][s] = logical[r][s^key]
    }
    // ---- stage W: 2048 slots (64 rows x 32), 4 per thread ----
    #pragma unroll
    for (int i = 0; i < 4; ++i) {
        const int q = t + i * 512;
        const int r = q >> 5, s = q & 31;
        const float* g = srcW + (size_t)r * KDIM + ((s ^ (r & 15)) * 8);
        const uint4 v = pack8_bf16(*(const float4*)g, *(const float4*)(g + 4));
        *(uint4*)&SH[16384 + (r * 32 + s) * 8] = v;
    }
    __syncthreads();

    const int fm = lane & 15;              // frag row/col AND swizzle key
    const int kq = lane >> 4;              // k-quad
    const int m0 = (wv & 3) * 16;          // 4 row strips
    const int n0 = (wv >> 2) * 32;         // 2 col halves

    const int arow  = (m0 + fm) * 256;
    const int wrow0 = 16384 + (n0 + fm) * 256;
    const int wrow1 = wrow0 + 16 * 256;

    float4v acc0 = {0.f, 0.f, 0.f, 0.f};
    float4v acc1 = {0.f, 0.f, 0.f, 0.f};

    // ---- inner: 8 k-steps x (3 ds_read_b128 + 2 MFMA), one barrier total ----
    #pragma unroll
    for (int ks = 0; ks < 8; ++ks) {
        const int so = ((ks * 4 + kq) ^ fm) * 8;   // swizzled short offset
        const short8 a  = *(const short8*)&SH[arow + so];
        const short8 b0 = *(const short8*)&SH[wrow0 + so];
        const short8 b1 = *(const short8*)&SH[wrow1 + so];
        acc0 = __builtin_amdgcn_mfma_f32_16x16x32_bf16(a, b0, acc0, 0, 0, 0);
        acc1 = __builtin_amdgcn_mfma_f32_16x16x32_bf16(a, b1, acc1, 0, 0, 0);
    }

    // ---- epilogue: scale + bias + tanh ----
    // C/D layout: col = lane&15, row = (lane>>4)*4 + reg   (m89)
    const int rbase = tile_r + m0 + kq * 4;
    const int c0 = tile_c + n0 + fm;
    const int c1 = c0 + 16;
    const float b0 = bias[c0], b1 = bias[c1];
    #pragma unroll
    for (int reg = 0; reg < 4; ++reg) {
        const int row = rbase + reg;
        const int n  = row & 3;
        const int li = (row >> 2) & 31;
        const float scale = (n == 0 || (n == 1 && li >= 16)) ? 1.0f : COEF;
        out[(size_t)row * COLS + c0] = tanh_fast(scale * acc0[reg] + b0);
        out[(size_t)row * COLS + c1] = tanh_fast(scale * acc1[reg] + b1);
    }
}

extern "C" void kernel_launch(void* const* d_in, const int* in_sizes, int n_in,
                              void* d_out, int out_size, void* d_ws, size_t ws_size,
                              hipStream_t stream) {
    const float* enc  = (const float*)d_in[0];   // [32, 512, 1024]
    const float* W    = (const float*)d_in[1];   // [256, 256]
    const float* bias = (const float*)d_in[2];   // [256]
    float* out = (float*)d_out;                  // [32, 32, 4, 256]

    dim3 grid(ROWS / TR, COLS / TC);             // 64 x 4 = 256 blocks (1/CU)
    spectral_mfma_kernel<<<grid, dim3(512), 0, stream>>>(enc, W, bias, out);
}